// Round 1
// baseline (2139.013 us; speedup 1.0000x reference)
//
#include <hip/hip_runtime.h>
#include <math.h>

// Problem constants (from reference)
#define NCLASS   128
#define ED       512        // E = FEAT*EMB
#define NROWS    131072     // N
#define BM       32         // rows per block in stage A (all same class)
#define EMBD     64
#define VDIM     32
#define TASKD    64
#define KCLUST   32

// workspace layout (float offsets)
#define WS_CNT   0                       // 128
#define WS_SSUM  128                     // 128*512
#define WS_SSQ   (128 + 65536)           // 128*512
#define WS_SIMP  (128 + 2*65536)         // 128  (always written, no zeroing needed)
#define WS_MEAN  (WS_SIMP + 128)         // 128*512
#define WS_MNORM (WS_MEAN + 65536)       // 128*512
#define WS_NC    (WS_MNORM + 65536)      // 128
#define WS_V     (WS_NC + 128)           // 128*32

// XOR swizzle: keeps float4 chunks intact (low 2 bits untouched) while
// spreading phase-0 write banks. Reads in the k-loop are wave-broadcast
// (all lanes same address) so the swizzle costs nothing there.
__device__ __forceinline__ int swz(int k, int r) { return k * 32 + (r ^ (k & 28)); }

// ---------------- Stage A: fused GEMM1+relu+GEMM2 + class stats ----------------
__global__ __launch_bounds__(256) void kA(const float* __restrict__ x,
                                          const int* __restrict__ y,
                                          const float* __restrict__ W0,
                                          const float* __restrict__ b0,
                                          const float* __restrict__ W1,
                                          const float* __restrict__ b1,
                                          float* __restrict__ ws)
{
    __shared__ float lds[ED * BM];   // exactly 64 KB: x-tile (transposed), then t-tile
    const int tid  = threadIdx.x;
    const int cls  = blockIdx.x & 127;   // presumed class (rows cls, cls+128, ...)
    const int seg  = blockIdx.x >> 7;    // which group of 32 shots
    const int base = seg * BM;

    // phase 0: load 32 rows of x, store transposed+swizzled
    {
        const int rr = tid >> 7;            // 0..1
        const int k4 = (tid & 127) * 4;     // 0..508
        for (int jj = 0; jj < 16; ++jj) {
            const int r = 2 * jj + rr;
            const long row = (long)cls + 128L * (base + r);
            const float4 xv = *(const float4*)(x + row * ED + k4);
            lds[swz(k4 + 0, r)] = xv.x;
            lds[swz(k4 + 1, r)] = xv.y;
            lds[swz(k4 + 2, r)] = xv.z;
            lds[swz(k4 + 3, r)] = xv.w;
        }
    }
    __syncthreads();

    const int c = tid;   // this thread owns output cols c and c+256
    float acc0[BM], acc1[BM];
    #pragma unroll
    for (int r = 0; r < BM; ++r) { acc0[r] = 0.f; acc1[r] = 0.f; }

    // phase 1: t = x @ W0
    #pragma unroll 2
    for (int k = 0; k < ED; ++k) {
        const float wa = W0[k * ED + c];
        const float wb = W0[k * ED + c + 256];
        #pragma unroll
        for (int rc = 0; rc < BM; rc += 4) {
            const float4 xv = *(const float4*)&lds[k * 32 + (rc ^ (k & 28))];
            acc0[rc + 0] += xv.x * wa;  acc1[rc + 0] += xv.x * wb;
            acc0[rc + 1] += xv.y * wa;  acc1[rc + 1] += xv.y * wb;
            acc0[rc + 2] += xv.z * wa;  acc1[rc + 2] += xv.z * wb;
            acc0[rc + 3] += xv.w * wa;  acc1[rc + 3] += xv.w * wb;
        }
    }
    const float ba = b0[c], bb = b0[c + 256];
    __syncthreads();   // all phase-1 LDS reads done before overwrite

    // write t = relu(acc + b0) back transposed (t's col index becomes k-dim)
    #pragma unroll
    for (int rc = 0; rc < BM; rc += 4) {
        float4 v0, v1;
        v0.x = fmaxf(acc0[rc + 0] + ba, 0.f);
        v0.y = fmaxf(acc0[rc + 1] + ba, 0.f);
        v0.z = fmaxf(acc0[rc + 2] + ba, 0.f);
        v0.w = fmaxf(acc0[rc + 3] + ba, 0.f);
        v1.x = fmaxf(acc1[rc + 0] + bb, 0.f);
        v1.y = fmaxf(acc1[rc + 1] + bb, 0.f);
        v1.z = fmaxf(acc1[rc + 2] + bb, 0.f);
        v1.w = fmaxf(acc1[rc + 3] + bb, 0.f);
        *(float4*)&lds[c * 32 + (rc ^ (c & 28))] = v0;
        *(float4*)&lds[(c + 256) * 32 + (rc ^ (c & 28))] = v1;  // (c+256)&28 == c&28
    }
    __syncthreads();

    // phase 2: h = t @ W1  (no relu)
    #pragma unroll
    for (int r = 0; r < BM; ++r) { acc0[r] = 0.f; acc1[r] = 0.f; }
    #pragma unroll 2
    for (int k = 0; k < ED; ++k) {
        const float wa = W1[k * ED + c];
        const float wb = W1[k * ED + c + 256];
        #pragma unroll
        for (int rc = 0; rc < BM; rc += 4) {
            const float4 tv = *(const float4*)&lds[k * 32 + (rc ^ (k & 28))];
            acc0[rc + 0] += tv.x * wa;  acc1[rc + 0] += tv.x * wb;
            acc0[rc + 1] += tv.y * wa;  acc1[rc + 1] += tv.y * wb;
            acc0[rc + 2] += tv.z * wa;  acc1[rc + 2] += tv.z * wb;
            acc0[rc + 3] += tv.w * wa;  acc1[rc + 3] += tv.w * wb;
        }
    }
    const float c0 = b1[c], c1 = b1[c + 256];
    #pragma unroll
    for (int r = 0; r < BM; ++r) { acc0[r] += c0; acc1[r] += c1; }

    // class stats. Fast path: all 32 rows share one class (true for y=i%128).
    const int y0 = y[(long)cls + 128L * base];
    bool uni = true;
    #pragma unroll
    for (int r = 1; r < BM; ++r) uni = uni && (y[(long)cls + 128L * (base + r)] == y0);

    float* cnt  = ws + WS_CNT;
    float* ssum = ws + WS_SSUM;
    float* ssq  = ws + WS_SSQ;
    if (uni) {
        float s0 = 0.f, q0 = 0.f, s1 = 0.f, q1 = 0.f;
        #pragma unroll
        for (int r = 0; r < BM; ++r) {
            s0 += acc0[r];  q0 += acc0[r] * acc0[r];
            s1 += acc1[r];  q1 += acc1[r] * acc1[r];
        }
        atomicAdd(&ssum[y0 * ED + c], s0);
        atomicAdd(&ssq [y0 * ED + c], q0);
        atomicAdd(&ssum[y0 * ED + c + 256], s1);
        atomicAdd(&ssq [y0 * ED + c + 256], q1);
        if (tid == 0) atomicAdd(&cnt[y0], (float)BM);
    } else {
        #pragma unroll
        for (int r = 0; r < BM; ++r) {
            const int yr = y[(long)cls + 128L * (base + r)];
            atomicAdd(&ssum[yr * ED + c], acc0[r]);
            atomicAdd(&ssq [yr * ED + c], acc0[r] * acc0[r]);
            atomicAdd(&ssum[yr * ED + c + 256], acc1[r]);
            atomicAdd(&ssq [yr * ED + c + 256], acc1[r] * acc1[r]);
        }
        if (tid == 0)
            for (int r = 0; r < BM; ++r)
                atomicAdd(&cnt[y[(long)cls + 128L * (base + r)]], 1.0f);
    }
}

// ---------------- Stage B1: per-class mean/var/mnorm + s/v MLP ----------------
__global__ __launch_bounds__(256) void kB1(const float* __restrict__ Ws,
                                           const float* __restrict__ bs,
                                           const float* __restrict__ Wv0,
                                           const float* __restrict__ bv0,
                                           const float* __restrict__ Wv1,
                                           const float* __restrict__ bv1,
                                           float* __restrict__ ws)
{
    __shared__ float sv[1025];   // [var(512) | mean(512) | Nc]
    __shared__ float red[256];
    __shared__ float sb[EMBD];
    __shared__ float pb[VDIM];
    const int cI = blockIdx.x, tid = threadIdx.x;
    const float* ssum = ws + WS_SSUM + cI * ED;
    const float* ssq  = ws + WS_SSQ  + cI * ED;
    const float cntv = ws[WS_CNT + cI];

    float nacc = 0.f;
    for (int e = tid; e < ED; e += 256) {
        const float m = ssum[e] / cntv;
        const float q = ssq[e];
        const float var = (q - cntv * m * m) / (cntv - 1.0f);
        sv[e] = var;
        sv[512 + e] = m;
        ws[WS_MEAN + cI * ED + e] = m;
        nacc += m * m;
    }
    if (tid == 0) {
        const float Ncv = (cntv - 1.0f) / 1023.0f;
        sv[1024] = Ncv;
        ws[WS_NC + cI] = Ncv;
    }
    red[tid] = nacc;
    __syncthreads();
    for (int off = 128; off > 0; off >>= 1) {
        if (tid < off) red[tid] += red[tid + off];
        __syncthreads();
    }
    const float inv = 1.0f / fmaxf(sqrtf(red[0]), 1e-7f);
    for (int e = tid; e < ED; e += 256)
        ws[WS_MNORM + cI * ED + e] = sv[512 + e] * inv;
    __syncthreads();

    if (tid < EMBD) {
        float a = bs[tid];
        for (int k = 0; k < 1025; ++k) a += sv[k] * Ws[k * EMBD + tid];
        sb[tid] = fmaxf(a, 0.f);
    }
    __syncthreads();
    if (tid < VDIM) {
        float a = bv0[tid];
        for (int k = 0; k < EMBD; ++k) a += sb[k] * Wv0[k * VDIM + tid];
        pb[tid] = fmaxf(a, 0.f);
    }
    __syncthreads();
    if (tid < VDIM) {
        float a = bv1[tid];
        for (int k = 0; k < VDIM; ++k) a += pb[k] * Wv1[k * VDIM + tid];
        ws[WS_V + cI * VDIM + tid] = a;
    }
}

// ---------------- Stage B2: weighted pairwise-cos partial sums ----------------
__global__ __launch_bounds__(128) void kB2(float* __restrict__ ws)
{
    __shared__ float mi[ED];
    __shared__ float red[128];
    const int i = blockIdx.x, tid = threadIdx.x;
    const float* mn = ws + WS_MNORM;
    for (int e = tid; e < ED; e += 128) mi[e] = mn[i * ED + e];
    __syncthreads();
    float contrib = 0.f;
    if (tid > i) {
        float d = 0.f;
        for (int e = 0; e < ED; ++e) d += mi[e] * mn[tid * ED + e];
        contrib = (float)(tid - i) * d;
    }
    red[tid] = contrib;
    __syncthreads();
    for (int off = 64; off > 0; off >>= 1) {
        if (tid < off) red[tid] += red[tid + off];
        __syncthreads();
    }
    if (tid == 0) ws[WS_SIMP + i] = red[0];
}

// ---------------- Stage B3: vv -> task -> cluster read-out ----------------
__global__ __launch_bounds__(128) void kB3(const float* __restrict__ W2,
                                           const float* __restrict__ b2,
                                           const float* __restrict__ mem,
                                           float* __restrict__ ws,
                                           float* __restrict__ out)
{
    __shared__ float vv[2 * VDIM + 2];
    __shared__ float task[TASKD];
    __shared__ float Cr[KCLUST];
    __shared__ float rsum;
    const int tid = threadIdx.x;
    const float* v = ws + WS_V;

    if (tid < VDIM) {
        float me = 0.f;
        for (int c = 0; c < NCLASS; ++c) me += v[c * VDIM + tid];
        me /= (float)NCLASS;
        float va = 0.f;
        for (int c = 0; c < NCLASS; ++c) {
            const float d = v[c * VDIM + tid] - me;
            va += d * d;
        }
        va /= (float)(NCLASS - 1);
        vv[tid] = va;
        vv[VDIM + tid] = me;
    }
    if (tid == 32 + VDIM) {   // any otherwise-idle thread
        float a = 0.f;
        for (int c = 0; c < NCLASS; ++c) a += ws[WS_NC + c];
        vv[2 * VDIM] = a / (float)NCLASS;
    }
    if (tid == 33 + VDIM) {
        float a = 0.f;
        for (int i = 0; i < NCLASS; ++i) a += ws[WS_SIMP + i];
        vv[2 * VDIM + 1] = a;
    }
    __syncthreads();
    if (tid < TASKD) {
        float a = b2[tid];
        for (int k = 0; k < 2 * VDIM + 2; ++k) a += vv[k] * W2[k * TASKD + tid];
        task[tid] = fmaxf(a, 0.f);
    }
    __syncthreads();
    if (tid < KCLUST) {
        float dd = 0.f;
        for (int e = 0; e < TASKD; ++e) {
            const float df = task[e] - mem[tid * TASKD + e];
            dd += df * df;
        }
        const float d = sqrtf(dd);
        // TEMP = 1: r = (d/TEMP + 1)^(-(TEMP+1)/2) = 1/(d+1)
        Cr[tid] = powf(d + 1.0f, -1.0f);
    }
    __syncthreads();
    if (tid == 0) {
        float a = 0.f;
        for (int k = 0; k < KCLUST; ++k) a += Cr[k];
        rsum = a;
    }
    __syncthreads();
    if (tid < TASKD) {
        float a = 0.f;
        for (int k = 0; k < KCLUST; ++k) a += (Cr[k] / rsum) * mem[k * TASKD + tid];
        out[tid] = a;
    }
}

extern "C" void kernel_launch(void* const* d_in, const int* in_sizes, int n_in,
                              void* d_out, int out_size, void* d_ws, size_t ws_size,
                              hipStream_t stream)
{
    const float* x   = (const float*)d_in[0];
    const int*   y   = (const int*)  d_in[1];
    const float* W0  = (const float*)d_in[2];
    const float* b0  = (const float*)d_in[3];
    const float* W1  = (const float*)d_in[4];
    const float* b1  = (const float*)d_in[5];
    const float* Ws  = (const float*)d_in[6];
    const float* bs  = (const float*)d_in[7];
    const float* Wv0 = (const float*)d_in[8];
    const float* bv0 = (const float*)d_in[9];
    const float* Wv1 = (const float*)d_in[10];
    const float* bv1 = (const float*)d_in[11];
    const float* W2  = (const float*)d_in[12];
    const float* b2  = (const float*)d_in[13];
    const float* mem = (const float*)d_in[14];
    float* out = (float*)d_out;
    float* ws  = (float*)d_ws;

    // zero cnt/ssum/ssq (atomic accumulators); ws is poisoned 0xAA each call
    hipMemsetAsync(ws, 0, (size_t)WS_SIMP * sizeof(float), stream);

    hipLaunchKernelGGL(kA,  dim3(NROWS / BM), dim3(256), 0, stream, x, y, W0, b0, W1, b1, ws);
    hipLaunchKernelGGL(kB1, dim3(NCLASS),     dim3(256), 0, stream, Ws, bs, Wv0, bv0, Wv1, bv1, ws);
    hipLaunchKernelGGL(kB2, dim3(NCLASS),     dim3(128), 0, stream, ws);
    hipLaunchKernelGGL(kB3, dim3(1),          dim3(128), 0, stream, W2, b2, mem, ws, out);
}

// Round 2
// 1067.136 us; speedup vs baseline: 2.0044x; 2.0044x over previous
//
#include <hip/hip_runtime.h>
#include <math.h>

typedef _Float16 f16;
typedef _Float16 f16x8 __attribute__((ext_vector_type(8)));
typedef float f32x4 __attribute__((ext_vector_type(4)));

// Problem constants
#define NCLASS   128
#define ED       512        // E = FEAT*EMB
#define NROWS    131072     // N
#define EMBD     64
#define VDIM     32
#define TASKD    64
#define KCLUST   32

// ---- workspace byte layout (fast path) ----
#define OFF_TH   0ull
#define OFF_TL   (OFF_TH  + (size_t)NROWS*ED*2)
#define OFF_W0H  (OFF_TL  + (size_t)NROWS*ED*2)
#define OFF_W0L  (OFF_W0H + (size_t)ED*ED*2)
#define OFF_W1H  (OFF_W0L + (size_t)ED*ED*2)
#define OFF_W1L  (OFF_W1H + (size_t)ED*ED*2)
#define OFF_STATS (OFF_W1L + (size_t)ED*ED*2)

// float offsets inside the stats region (round-1 layout)
#define WS_CNT   0
#define WS_SSUM  128
#define WS_SSQ   (128 + 65536)
#define WS_SIMP  (128 + 2*65536)
#define WS_MEAN  (WS_SIMP + 128)
#define WS_MNORM (WS_MEAN + 65536)
#define WS_NC    (WS_MNORM + 65536)
#define WS_V     (WS_NC + 128)
#define STATS_FLOATS (WS_V + NCLASS*VDIM)
#define WS_NEEDED (OFF_STATS + (size_t)STATS_FLOATS*4)

// =====================================================================
// Prep: split W0/W1 into f16 hi/lo, k-packed layout Wp[((k>>3)*512+n)*8+(k&7)]
// so a B-fragment (8 consecutive k at fixed n) is one contiguous 16-B load.
// =====================================================================
__global__ __launch_bounds__(256) void kPrep(const float* __restrict__ W0,
                                             const float* __restrict__ W1,
                                             f16* __restrict__ w0h, f16* __restrict__ w0l,
                                             f16* __restrict__ w1h, f16* __restrict__ w1l)
{
    const int idx = blockIdx.x * 256 + threadIdx.x;    // 0 .. 2*512*512-1
    const int sel = idx >= ED * ED;
    const float* W = sel ? W1 : W0;
    f16* oh = sel ? w1h : w0h;
    f16* ol = sel ? w1l : w0l;
    const int e = idx & (ED * ED - 1);
    const int k = e >> 9, n = e & 511;
    const float w = W[e];
    const f16 hi = (f16)w;
    const f16 lo = (f16)(w - (float)hi);
    const int o = ((k >> 3) * ED + n) * 8 + (k & 7);
    oh[o] = hi;
    ol[o] = lo;
}

// =====================================================================
// Split-f16 MFMA GEMM.  MODE 0: t = relu(x@W0+b0), x gathered class-grouped,
// output split-f16 row-major t'[v][k] (v = class*1024 + shot).
// MODE 1: h = t'@W1+b1 fused with per-class ssum/ssq/cnt atomics.
// Block: 128 rows x 128 cols, 256 threads = 4 waves (2x2 of 64x64).
// 3 MFMAs per tile per k-step: Ah*Bh + Ah*Bl + Al*Bh (fp32 accumulate).
// =====================================================================
template<int MODE>
__global__ __launch_bounds__(256) void kGemm(
    const float* __restrict__ xf,       // MODE 0
    const f16*  __restrict__ ah_g,      // MODE 1: t_hi
    const f16*  __restrict__ al_g,      // MODE 1: t_lo
    const f16*  __restrict__ bh,        // prepped W hi
    const f16*  __restrict__ bl,        // prepped W lo
    const float* __restrict__ bias,     // b0 / b1
    const int*  __restrict__ y,
    f16* __restrict__ th, f16* __restrict__ tl,   // MODE 0 out
    float* __restrict__ stats)                    // MODE 1 out
{
    // A tiles in LDS, row-major with +8-half pad (row stride 40 halfs = 80 B)
    __shared__ f16 Ah[128 * 40];
    __shared__ f16 Al[128 * 40];

    const int tid  = threadIdx.x;
    const int lane = tid & 63;
    const int wid  = tid >> 6;
    const int wr   = wid >> 1;          // wave row (0..1)
    const int wc   = wid & 1;           // wave col (0..1)
    const int colb = blockIdx.x & 3;
    const int rowb = blockIdx.x >> 2;
    const int v0   = rowb * 128;        // class-grouped virtual row base
    const int n0   = colb * 128;

    f32x4 acc[16];
    #pragma unroll
    for (int i = 0; i < 16; ++i) acc[i] = (f32x4){0.f, 0.f, 0.f, 0.f};

    const int q   = lane >> 4;          // quad 0..3
    const int ln  = lane & 15;

    for (int ks = 0; ks < 16; ++ks) {
        const int k0 = ks * 32;
        __syncthreads();                 // prior k-step's LDS reads done

        if (MODE == 0) {
            // stage + convert x: thread -> row tid>>1, 16 k's at (tid&1)*16
            const int r  = tid >> 1;
            const int kb = (tid & 1) * 16;
            const int gv = v0 + r;
            const long orig = (long)(gv >> 10) + 128L * (gv & 1023);
            const float* src = xf + orig * ED + k0 + kb;
            float vbuf[16];
            *(float4*)(vbuf + 0)  = *(const float4*)(src + 0);
            *(float4*)(vbuf + 4)  = *(const float4*)(src + 4);
            *(float4*)(vbuf + 8)  = *(const float4*)(src + 8);
            *(float4*)(vbuf + 12) = *(const float4*)(src + 12);
            f16x8 h0, h1, l0, l1;
            #pragma unroll
            for (int i = 0; i < 8; ++i) {
                float w = vbuf[i];     f16 h = (f16)w; h0[i] = h; l0[i] = (f16)(w - (float)h);
                float w2 = vbuf[8+i];  f16 h2 = (f16)w2; h1[i] = h2; l1[i] = (f16)(w2 - (float)h2);
            }
            *(f16x8*)&Ah[r * 40 + kb]     = h0;
            *(f16x8*)&Ah[r * 40 + kb + 8] = h1;
            *(f16x8*)&Al[r * 40 + kb]     = l0;
            *(f16x8*)&Al[r * 40 + kb + 8] = l1;
        } else {
            // stage t' (already split): 2 passes x 16-B chunks
            #pragma unroll
            for (int p = 0; p < 2; ++p) {
                const int flat = tid + p * 256;       // 0..511
                const int r   = flat >> 2;
                const int seg = (flat & 3) * 8;
                const long go = (long)(v0 + r) * ED + k0 + seg;
                *(f16x8*)&Ah[r * 40 + seg] = *(const f16x8*)(ah_g + go);
                *(f16x8*)&Al[r * 40 + seg] = *(const f16x8*)(al_g + go);
            }
        }
        __syncthreads();

        // B fragments straight from L2 (prepped layout, contiguous 16 B/lane)
        const long kg0  = (long)(ks * 4 + q);
        const int  bcol = n0 + wc * 64 + ln;
        f16x8 bhF[4], blF[4];
        #pragma unroll
        for (int ct = 0; ct < 4; ++ct) {
            const long bo = (kg0 * ED + bcol + ct * 16) * 8;
            bhF[ct] = *(const f16x8*)(bh + bo);
            blF[ct] = *(const f16x8*)(bl + bo);
        }
        // A fragments from LDS
        const int arow = wr * 64 + ln;
        const int akq  = q * 8;
        f16x8 ahF[4], alF[4];
        #pragma unroll
        for (int rt = 0; rt < 4; ++rt) {
            ahF[rt] = *(const f16x8*)&Ah[(arow + rt * 16) * 40 + akq];
            alF[rt] = *(const f16x8*)&Al[(arow + rt * 16) * 40 + akq];
        }
        #pragma unroll
        for (int ct = 0; ct < 4; ++ct)
            #pragma unroll
            for (int rt = 0; rt < 4; ++rt) {
                f32x4 c = acc[rt * 4 + ct];
                c = __builtin_amdgcn_mfma_f32_16x16x32_f16(alF[rt], bhF[ct], c, 0, 0, 0);
                c = __builtin_amdgcn_mfma_f32_16x16x32_f16(ahF[rt], blF[ct], c, 0, 0, 0);
                c = __builtin_amdgcn_mfma_f32_16x16x32_f16(ahF[rt], bhF[ct], c, 0, 0, 0);
                acc[rt * 4 + ct] = c;
            }
    }

    // ---------------- epilogue ----------------
    // C/D layout (16x16): m-row = q*4 + reg, n-col = lane&15  [m89/m91]
    if (MODE == 0) {
        #pragma unroll
        for (int ct = 0; ct < 4; ++ct) {
            const int col = n0 + wc * 64 + ct * 16 + ln;
            const float bv = bias[col];
            #pragma unroll
            for (int rt = 0; rt < 4; ++rt) {
                const int rbase = v0 + wr * 64 + rt * 16 + q * 4;
                #pragma unroll
                for (int rg = 0; rg < 4; ++rg) {
                    float t = fmaxf(acc[rt * 4 + ct][rg] + bv, 0.f);
                    const f16 hi = (f16)t;
                    const f16 lo = (f16)(t - (float)hi);
                    th[(long)(rbase + rg) * ED + col] = hi;
                    tl[(long)(rbase + rg) * ED + col] = lo;
                }
            }
        }
    } else {
        // all 128 rows of this block are one class (class-grouped order)
        const int j0 = v0 & 1023;
        const int cls = y[(long)(v0 >> 10) + 128L * j0];
        float* cnt  = stats + WS_CNT;
        float* ssum = stats + WS_SSUM;
        float* ssq  = stats + WS_SSQ;
        #pragma unroll
        for (int ct = 0; ct < 4; ++ct) {
            const int col = n0 + wc * 64 + ct * 16 + ln;
            const float bv = bias[col];
            float s = 0.f, qq = 0.f;
            #pragma unroll
            for (int rt = 0; rt < 4; ++rt)
                #pragma unroll
                for (int rg = 0; rg < 4; ++rg) {
                    const float h = acc[rt * 4 + ct][rg] + bv;
                    s += h; qq += h * h;
                }
            s  += __shfl_xor(s, 16);  qq += __shfl_xor(qq, 16);
            s  += __shfl_xor(s, 32);  qq += __shfl_xor(qq, 32);
            if (ln == lane) {}       // no-op, keep structure
            if (lane < 16) {
                atomicAdd(&ssum[cls * ED + col], s);
                atomicAdd(&ssq [cls * ED + col], qq);
            }
        }
        if (tid == 0 && colb == 0) atomicAdd(&cnt[cls], 128.0f);
    }
}

// =====================================================================
// Round-1 fp32 fallback (used only if ws_size is too small)
// =====================================================================
__device__ __forceinline__ int swz(int k, int r) { return k * 32 + (r ^ (k & 28)); }

__global__ __launch_bounds__(256) void kA(const float* __restrict__ x,
                                          const int* __restrict__ y,
                                          const float* __restrict__ W0,
                                          const float* __restrict__ b0,
                                          const float* __restrict__ W1,
                                          const float* __restrict__ b1,
                                          float* __restrict__ ws)
{
    __shared__ float lds[ED * 32];
    const int tid  = threadIdx.x;
    const int cls  = blockIdx.x & 127;
    const int seg  = blockIdx.x >> 7;
    const int base = seg * 32;
    {
        const int rr = tid >> 7;
        const int k4 = (tid & 127) * 4;
        for (int jj = 0; jj < 16; ++jj) {
            const int r = 2 * jj + rr;
            const long row = (long)cls + 128L * (base + r);
            const float4 xv = *(const float4*)(x + row * ED + k4);
            lds[swz(k4 + 0, r)] = xv.x;
            lds[swz(k4 + 1, r)] = xv.y;
            lds[swz(k4 + 2, r)] = xv.z;
            lds[swz(k4 + 3, r)] = xv.w;
        }
    }
    __syncthreads();
    const int c = tid;
    float acc0[32], acc1[32];
    #pragma unroll
    for (int r = 0; r < 32; ++r) { acc0[r] = 0.f; acc1[r] = 0.f; }
    #pragma unroll 2
    for (int k = 0; k < ED; ++k) {
        const float wa = W0[k * ED + c];
        const float wb = W0[k * ED + c + 256];
        #pragma unroll
        for (int rc = 0; rc < 32; rc += 4) {
            const float4 xv = *(const float4*)&lds[k * 32 + (rc ^ (k & 28))];
            acc0[rc+0] += xv.x * wa; acc1[rc+0] += xv.x * wb;
            acc0[rc+1] += xv.y * wa; acc1[rc+1] += xv.y * wb;
            acc0[rc+2] += xv.z * wa; acc1[rc+2] += xv.z * wb;
            acc0[rc+3] += xv.w * wa; acc1[rc+3] += xv.w * wb;
        }
    }
    const float ba = b0[c], bb = b0[c + 256];
    __syncthreads();
    #pragma unroll
    for (int rc = 0; rc < 32; rc += 4) {
        float4 v0, v1;
        v0.x = fmaxf(acc0[rc+0] + ba, 0.f); v0.y = fmaxf(acc0[rc+1] + ba, 0.f);
        v0.z = fmaxf(acc0[rc+2] + ba, 0.f); v0.w = fmaxf(acc0[rc+3] + ba, 0.f);
        v1.x = fmaxf(acc1[rc+0] + bb, 0.f); v1.y = fmaxf(acc1[rc+1] + bb, 0.f);
        v1.z = fmaxf(acc1[rc+2] + bb, 0.f); v1.w = fmaxf(acc1[rc+3] + bb, 0.f);
        *(float4*)&lds[c * 32 + (rc ^ (c & 28))] = v0;
        *(float4*)&lds[(c + 256) * 32 + (rc ^ (c & 28))] = v1;
    }
    __syncthreads();
    #pragma unroll
    for (int r = 0; r < 32; ++r) { acc0[r] = 0.f; acc1[r] = 0.f; }
    #pragma unroll 2
    for (int k = 0; k < ED; ++k) {
        const float wa = W1[k * ED + c];
        const float wb = W1[k * ED + c + 256];
        #pragma unroll
        for (int rc = 0; rc < 32; rc += 4) {
            const float4 tv = *(const float4*)&lds[k * 32 + (rc ^ (k & 28))];
            acc0[rc+0] += tv.x * wa; acc1[rc+0] += tv.x * wb;
            acc0[rc+1] += tv.y * wa; acc1[rc+1] += tv.y * wb;
            acc0[rc+2] += tv.z * wa; acc1[rc+2] += tv.z * wb;
            acc0[rc+3] += tv.w * wa; acc1[rc+3] += tv.w * wb;
        }
    }
    const float c0 = b1[c], c1 = b1[c + 256];
    #pragma unroll
    for (int r = 0; r < 32; ++r) { acc0[r] += c0; acc1[r] += c1; }
    const int y0 = y[(long)cls + 128L * base];
    bool uni = true;
    #pragma unroll
    for (int r = 1; r < 32; ++r) uni = uni && (y[(long)cls + 128L * (base + r)] == y0);
    float* cnt  = ws + WS_CNT;
    float* ssum = ws + WS_SSUM;
    float* ssq  = ws + WS_SSQ;
    if (uni) {
        float s0 = 0.f, q0 = 0.f, s1 = 0.f, q1 = 0.f;
        #pragma unroll
        for (int r = 0; r < 32; ++r) {
            s0 += acc0[r]; q0 += acc0[r] * acc0[r];
            s1 += acc1[r]; q1 += acc1[r] * acc1[r];
        }
        atomicAdd(&ssum[y0 * ED + c], s0);
        atomicAdd(&ssq [y0 * ED + c], q0);
        atomicAdd(&ssum[y0 * ED + c + 256], s1);
        atomicAdd(&ssq [y0 * ED + c + 256], q1);
        if (tid == 0) atomicAdd(&cnt[y0], 32.0f);
    } else {
        #pragma unroll
        for (int r = 0; r < 32; ++r) {
            const int yr = y[(long)cls + 128L * (base + r)];
            atomicAdd(&ssum[yr * ED + c], acc0[r]);
            atomicAdd(&ssq [yr * ED + c], acc0[r] * acc0[r]);
            atomicAdd(&ssum[yr * ED + c + 256], acc1[r]);
            atomicAdd(&ssq [yr * ED + c + 256], acc1[r] * acc1[r]);
        }
        if (tid == 0)
            for (int r = 0; r < 32; ++r)
                atomicAdd(&cnt[y[(long)cls + 128L * (base + r)]], 1.0f);
    }
}

// ---------------- Stage B1: per-class mean/var/mnorm + s/v MLP ----------------
__global__ __launch_bounds__(256) void kB1(const float* __restrict__ Ws,
                                           const float* __restrict__ bs,
                                           const float* __restrict__ Wv0,
                                           const float* __restrict__ bv0,
                                           const float* __restrict__ Wv1,
                                           const float* __restrict__ bv1,
                                           float* __restrict__ ws)
{
    __shared__ float sv[1025];
    __shared__ float red[256];
    __shared__ float sb[EMBD];
    __shared__ float pb[VDIM];
    const int cI = blockIdx.x, tid = threadIdx.x;
    const float* ssum = ws + WS_SSUM + cI * ED;
    const float* ssq  = ws + WS_SSQ  + cI * ED;
    const float cntv = ws[WS_CNT + cI];

    float nacc = 0.f;
    for (int e = tid; e < ED; e += 256) {
        const float m = ssum[e] / cntv;
        const float qv = ssq[e];
        const float var = (qv - cntv * m * m) / (cntv - 1.0f);
        sv[e] = var;
        sv[512 + e] = m;
        ws[WS_MEAN + cI * ED + e] = m;
        nacc += m * m;
    }
    if (tid == 0) {
        const float Ncv = (cntv - 1.0f) / 1023.0f;
        sv[1024] = Ncv;
        ws[WS_NC + cI] = Ncv;
    }
    red[tid] = nacc;
    __syncthreads();
    for (int off = 128; off > 0; off >>= 1) {
        if (tid < off) red[tid] += red[tid + off];
        __syncthreads();
    }
    const float inv = 1.0f / fmaxf(sqrtf(red[0]), 1e-7f);
    for (int e = tid; e < ED; e += 256)
        ws[WS_MNORM + cI * ED + e] = sv[512 + e] * inv;
    __syncthreads();

    if (tid < EMBD) {
        float a = bs[tid];
        for (int k = 0; k < 1025; ++k) a += sv[k] * Ws[k * EMBD + tid];
        sb[tid] = fmaxf(a, 0.f);
    }
    __syncthreads();
    if (tid < VDIM) {
        float a = bv0[tid];
        for (int k = 0; k < EMBD; ++k) a += sb[k] * Wv0[k * VDIM + tid];
        pb[tid] = fmaxf(a, 0.f);
    }
    __syncthreads();
    if (tid < VDIM) {
        float a = bv1[tid];
        for (int k = 0; k < VDIM; ++k) a += pb[k] * Wv1[k * VDIM + tid];
        ws[WS_V + cI * VDIM + tid] = a;
    }
}

// ---------------- Stage B2: weighted pairwise-cos partial sums ----------------
__global__ __launch_bounds__(128) void kB2(float* __restrict__ ws)
{
    __shared__ float mi[ED];
    __shared__ float red[128];
    const int i = blockIdx.x, tid = threadIdx.x;
    const float* mn = ws + WS_MNORM;
    for (int e = tid; e < ED; e += 128) mi[e] = mn[i * ED + e];
    __syncthreads();
    float contrib = 0.f;
    if (tid > i) {
        float d = 0.f;
        for (int e = 0; e < ED; ++e) d += mi[e] * mn[tid * ED + e];
        contrib = (float)(tid - i) * d;
    }
    red[tid] = contrib;
    __syncthreads();
    for (int off = 64; off > 0; off >>= 1) {
        if (tid < off) red[tid] += red[tid + off];
        __syncthreads();
    }
    if (tid == 0) ws[WS_SIMP + i] = red[0];
}

// ---------------- Stage B3: vv -> task -> cluster read-out ----------------
__global__ __launch_bounds__(128) void kB3(const float* __restrict__ W2,
                                           const float* __restrict__ b2,
                                           const float* __restrict__ mem,
                                           float* __restrict__ ws,
                                           float* __restrict__ out)
{
    __shared__ float vv[2 * VDIM + 2];
    __shared__ float task[TASKD];
    __shared__ float Cr[KCLUST];
    __shared__ float rsum;
    const int tid = threadIdx.x;
    const float* v = ws + WS_V;

    if (tid < VDIM) {
        float me = 0.f;
        for (int c = 0; c < NCLASS; ++c) me += v[c * VDIM + tid];
        me /= (float)NCLASS;
        float va = 0.f;
        for (int c = 0; c < NCLASS; ++c) {
            const float d = v[c * VDIM + tid] - me;
            va += d * d;
        }
        va /= (float)(NCLASS - 1);
        vv[tid] = va;
        vv[VDIM + tid] = me;
    }
    if (tid == 32 + VDIM) {
        float a = 0.f;
        for (int c = 0; c < NCLASS; ++c) a += ws[WS_NC + c];
        vv[2 * VDIM] = a / (float)NCLASS;
    }
    if (tid == 33 + VDIM) {
        float a = 0.f;
        for (int i = 0; i < NCLASS; ++i) a += ws[WS_SIMP + i];
        vv[2 * VDIM + 1] = a;
    }
    __syncthreads();
    if (tid < TASKD) {
        float a = b2[tid];
        for (int k = 0; k < 2 * VDIM + 2; ++k) a += vv[k] * W2[k * TASKD + tid];
        task[tid] = fmaxf(a, 0.f);
    }
    __syncthreads();
    if (tid < KCLUST) {
        float dd = 0.f;
        for (int e = 0; e < TASKD; ++e) {
            const float df = task[e] - mem[tid * TASKD + e];
            dd += df * df;
        }
        const float d = sqrtf(dd);
        Cr[tid] = 1.0f / (d + 1.0f);    // TEMP=1: (d+1)^-1
    }
    __syncthreads();
    if (tid == 0) {
        float a = 0.f;
        for (int k = 0; k < KCLUST; ++k) a += Cr[k];
        rsum = a;
    }
    __syncthreads();
    if (tid < TASKD) {
        float a = 0.f;
        for (int k = 0; k < KCLUST; ++k) a += (Cr[k] / rsum) * mem[k * TASKD + tid];
        out[tid] = a;
    }
}

extern "C" void kernel_launch(void* const* d_in, const int* in_sizes, int n_in,
                              void* d_out, int out_size, void* d_ws, size_t ws_size,
                              hipStream_t stream)
{
    const float* x   = (const float*)d_in[0];
    const int*   y   = (const int*)  d_in[1];
    const float* W0  = (const float*)d_in[2];
    const float* b0  = (const float*)d_in[3];
    const float* W1  = (const float*)d_in[4];
    const float* b1  = (const float*)d_in[5];
    const float* Ws  = (const float*)d_in[6];
    const float* bs  = (const float*)d_in[7];
    const float* Wv0 = (const float*)d_in[8];
    const float* bv0 = (const float*)d_in[9];
    const float* Wv1 = (const float*)d_in[10];
    const float* bv1 = (const float*)d_in[11];
    const float* W2  = (const float*)d_in[12];
    const float* b2  = (const float*)d_in[13];
    const float* mem = (const float*)d_in[14];
    float* out = (float*)d_out;

    if (ws_size >= WS_NEEDED) {
        char* wsb = (char*)d_ws;
        f16* th  = (f16*)(wsb + OFF_TH);
        f16* tl  = (f16*)(wsb + OFF_TL);
        f16* w0h = (f16*)(wsb + OFF_W0H);
        f16* w0l = (f16*)(wsb + OFF_W0L);
        f16* w1h = (f16*)(wsb + OFF_W1H);
        f16* w1l = (f16*)(wsb + OFF_W1L);
        float* stats = (float*)(wsb + OFF_STATS);

        hipMemsetAsync(stats, 0, (size_t)WS_SIMP * sizeof(float), stream);
        hipLaunchKernelGGL(kPrep, dim3(2 * ED * ED / 256), dim3(256), 0, stream,
                           W0, W1, w0h, w0l, w1h, w1l);
        hipLaunchKernelGGL((kGemm<0>), dim3(4096), dim3(256), 0, stream,
                           x, (const f16*)nullptr, (const f16*)nullptr,
                           w0h, w0l, b0, y, th, tl, (float*)nullptr);
        hipLaunchKernelGGL((kGemm<1>), dim3(4096), dim3(256), 0, stream,
                           (const float*)nullptr, th, tl,
                           w1h, w1l, b1, y, (f16*)nullptr, (f16*)nullptr, stats);
        hipLaunchKernelGGL(kB1, dim3(NCLASS), dim3(256), 0, stream, Ws, bs, Wv0, bv0, Wv1, bv1, stats);
        hipLaunchKernelGGL(kB2, dim3(NCLASS), dim3(128), 0, stream, stats);
        hipLaunchKernelGGL(kB3, dim3(1), dim3(128), 0, stream, W2, b2, mem, stats, out);
    } else {
        float* ws = (float*)d_ws;
        hipMemsetAsync(ws, 0, (size_t)WS_SIMP * sizeof(float), stream);
        hipLaunchKernelGGL(kA,  dim3(NROWS / 32), dim3(256), 0, stream, x, y, W0, b0, W1, b1, ws);
        hipLaunchKernelGGL(kB1, dim3(NCLASS), dim3(256), 0, stream, Ws, bs, Wv0, bv0, Wv1, bv1, ws);
        hipLaunchKernelGGL(kB2, dim3(NCLASS), dim3(128), 0, stream, ws);
        hipLaunchKernelGGL(kB3, dim3(1), dim3(128), 0, stream, W2, b2, mem, ws, out);
    }
}

// Round 3
// 928.175 us; speedup vs baseline: 2.3045x; 1.1497x over previous
//
#include <hip/hip_runtime.h>
#include <math.h>

typedef _Float16 f16;
typedef _Float16 f16x8 __attribute__((ext_vector_type(8)));
typedef _Float16 f16x4 __attribute__((ext_vector_type(4)));
typedef float f32x4 __attribute__((ext_vector_type(4)));

// Problem constants
#define NCLASS   128
#define ED       512        // E = FEAT*EMB
#define NROWS    131072     // N
#define EMBD     64
#define VDIM     32
#define TASKD    64
#define KCLUST   32

// ---- workspace byte layout (fast path): W splits + stats only ----
#define OFF_W0H  0ull
#define OFF_W0L  (OFF_W0H + (size_t)ED*ED*2)
#define OFF_W1H  (OFF_W0L + (size_t)ED*ED*2)
#define OFF_W1L  (OFF_W1H + (size_t)ED*ED*2)
#define OFF_STATS (OFF_W1L + (size_t)ED*ED*2)

// float offsets inside the stats region
#define WS_CNT   0
#define WS_SSUM  128
#define WS_SSQ   (128 + 65536)
#define WS_SIMP  (128 + 2*65536)
#define WS_MEAN  (WS_SIMP + 128)
#define WS_MNORM (WS_MEAN + 65536)
#define WS_NC    (WS_MNORM + 65536)
#define WS_V     (WS_NC + 128)
#define STATS_FLOATS (WS_V + NCLASS*VDIM)
#define WS_NEEDED (OFF_STATS + (size_t)STATS_FLOATS*4)

// LDS t/x tile: 64 rows x 512 k, split f16, row stride 520 halfs (+8 pad).
// Row stride 1040 B == 4-bank shift per row -> 2-way (free) on b128 frag reads.
#define TROW 520

// =====================================================================
// Prep: split W0/W1 into f16 hi/lo, k-packed layout Wp[((k>>3)*512+n)*8+(k&7)]
// so a B-fragment (8 consecutive k at fixed n) is one contiguous 16-B load.
// =====================================================================
__global__ __launch_bounds__(256) void kPrep(const float* __restrict__ W0,
                                             const float* __restrict__ W1,
                                             f16* __restrict__ w0h, f16* __restrict__ w0l,
                                             f16* __restrict__ w1h, f16* __restrict__ w1l)
{
    const int idx = blockIdx.x * 256 + threadIdx.x;    // 0 .. 2*512*512-1
    const int sel = idx >= ED * ED;
    const float* W = sel ? W1 : W0;
    f16* oh = sel ? w1h : w0h;
    f16* ol = sel ? w1l : w0l;
    const int e = idx & (ED * ED - 1);
    const int k = e >> 9, n = e & 511;
    const float w = W[e];
    const f16 hi = (f16)w;
    const f16 lo = (f16)(w - (float)hi);
    const int o = ((k >> 3) * ED + n) * 8 + (k & 7);
    oh[o] = hi;
    ol[o] = lo;
}

// =====================================================================
// Fused: t = relu(x@W0+b0) kept in LDS (split f16), h = t@W1+b1 reduced
// directly into per-class ssum/ssq/cnt. Block = 64 rows (one class) x all
// 512 cols; 512 threads = 8 waves, each wave 64 rows x 64 cols.
// 3 MFMAs per tile (Al*Bh + Ah*Bl + Ah*Bh), fp32 accumulate -> ~fp32 acc.
// Only 3 __syncthreads in the whole kernel.
// =====================================================================
__global__ __launch_bounds__(512, 2) void kFused(
    const float* __restrict__ x,
    const int*   __restrict__ y,
    const f16*  __restrict__ w0h, const f16* __restrict__ w0l,
    const float* __restrict__ b0,
    const f16*  __restrict__ w1h, const f16* __restrict__ w1l,
    const float* __restrict__ b1,
    float* __restrict__ stats)
{
    __shared__ f16 Th[64 * TROW];   // 66,560 B
    __shared__ f16 Tl[64 * TROW];   // 66,560 B  (total 133,120 B -> 1 block/CU)

    const int tid  = threadIdx.x;
    const int lane = tid & 63;
    const int wid  = tid >> 6;          // 0..7 = column group
    const int q    = lane >> 4;         // quad 0..3 -> k-sub-block q*8
    const int ln   = lane & 15;
    const int ncol0 = wid * 64;

    const int cls   = blockIdx.x >> 4;          // v0>>10, v0 = blockIdx.x*64
    const int shot0 = (blockIdx.x & 15) * 64;   // v0 & 1023

    // ---- phase 0: stage x-tile (64x512), split into f16 hi/lo ----
    #pragma unroll 4
    for (int i = 0; i < 16; ++i) {
        const int flat = tid + i * 512;         // 0..8191 float4s
        const int row  = flat >> 7;             // 128 float4 per row
        const int c4   = (flat & 127) << 2;
        const long orig = (long)cls + 128L * (shot0 + row);
        const float4 xv = *(const float4*)(x + orig * ED + c4);
        f16x4 hv, lv;
        hv[0] = (f16)xv.x; lv[0] = (f16)(xv.x - (float)hv[0]);
        hv[1] = (f16)xv.y; lv[1] = (f16)(xv.y - (float)hv[1]);
        hv[2] = (f16)xv.z; lv[2] = (f16)(xv.z - (float)hv[2]);
        hv[3] = (f16)xv.w; lv[3] = (f16)(xv.w - (float)hv[3]);
        *(f16x4*)&Th[row * TROW + c4] = hv;
        *(f16x4*)&Tl[row * TROW + c4] = lv;
    }
    __syncthreads();

    f32x4 acc[16];
    #pragma unroll
    for (int i = 0; i < 16; ++i) acc[i] = (f32x4){0.f, 0.f, 0.f, 0.f};

    // ---- phase 1: GEMM1, A = x-tile (LDS), B = W0 (L2), no barriers ----
    for (int ks = 0; ks < 16; ++ks) {
        const int k0 = ks * 32;
        f16x8 aH[4], aL[4], bH[4], bL[4];
        #pragma unroll
        for (int rt = 0; rt < 4; ++rt) {
            const int row = rt * 16 + ln;
            aH[rt] = *(const f16x8*)&Th[row * TROW + k0 + q * 8];
            aL[rt] = *(const f16x8*)&Tl[row * TROW + k0 + q * 8];
        }
        const long kg = ks * 4 + q;
        #pragma unroll
        for (int ct = 0; ct < 4; ++ct) {
            const long bo = (kg * ED + ncol0 + ct * 16 + ln) * 8;
            bH[ct] = *(const f16x8*)(w0h + bo);
            bL[ct] = *(const f16x8*)(w0l + bo);
        }
        #pragma unroll
        for (int ct = 0; ct < 4; ++ct)
            #pragma unroll
            for (int rt = 0; rt < 4; ++rt) {
                f32x4 c = acc[rt * 4 + ct];
                c = __builtin_amdgcn_mfma_f32_16x16x32_f16(aL[rt], bH[ct], c, 0, 0, 0);
                c = __builtin_amdgcn_mfma_f32_16x16x32_f16(aH[rt], bL[ct], c, 0, 0, 0);
                c = __builtin_amdgcn_mfma_f32_16x16x32_f16(aH[rt], bH[ct], c, 0, 0, 0);
                acc[rt * 4 + ct] = c;
            }
    }
    __syncthreads();   // everyone done reading x-tile

    // ---- write t = relu(acc+b0) split back into the same LDS tile ----
    // C/D layout (16x16): m = q*4 + reg, n = lane&15
    #pragma unroll
    for (int ct = 0; ct < 4; ++ct) {
        const int col = ncol0 + ct * 16 + ln;
        const float bv = b0[col];
        #pragma unroll
        for (int rt = 0; rt < 4; ++rt) {
            const int rbase = rt * 16 + q * 4;
            #pragma unroll
            for (int rg = 0; rg < 4; ++rg) {
                const float t = fmaxf(acc[rt * 4 + ct][rg] + bv, 0.f);
                const f16 hi = (f16)t;
                const f16 lo = (f16)(t - (float)hi);
                Th[(rbase + rg) * TROW + col] = hi;
                Tl[(rbase + rg) * TROW + col] = lo;
            }
        }
    }
    __syncthreads();   // t-tile complete

    #pragma unroll
    for (int i = 0; i < 16; ++i) acc[i] = (f32x4){0.f, 0.f, 0.f, 0.f};

    // ---- phase 2: GEMM2, A = t-tile (LDS), B = W1 (L2), no barriers ----
    for (int ks = 0; ks < 16; ++ks) {
        const int k0 = ks * 32;
        f16x8 aH[4], aL[4], bH[4], bL[4];
        #pragma unroll
        for (int rt = 0; rt < 4; ++rt) {
            const int row = rt * 16 + ln;
            aH[rt] = *(const f16x8*)&Th[row * TROW + k0 + q * 8];
            aL[rt] = *(const f16x8*)&Tl[row * TROW + k0 + q * 8];
        }
        const long kg = ks * 4 + q;
        #pragma unroll
        for (int ct = 0; ct < 4; ++ct) {
            const long bo = (kg * ED + ncol0 + ct * 16 + ln) * 8;
            bH[ct] = *(const f16x8*)(w1h + bo);
            bL[ct] = *(const f16x8*)(w1l + bo);
        }
        #pragma unroll
        for (int ct = 0; ct < 4; ++ct)
            #pragma unroll
            for (int rt = 0; rt < 4; ++rt) {
                f32x4 c = acc[rt * 4 + ct];
                c = __builtin_amdgcn_mfma_f32_16x16x32_f16(aL[rt], bH[ct], c, 0, 0, 0);
                c = __builtin_amdgcn_mfma_f32_16x16x32_f16(aH[rt], bL[ct], c, 0, 0, 0);
                c = __builtin_amdgcn_mfma_f32_16x16x32_f16(aH[rt], bH[ct], c, 0, 0, 0);
                acc[rt * 4 + ct] = c;
            }
    }

    // ---- epilogue: per-class stats (all 64 rows are one class) ----
    const int clsY = y[(long)cls + 128L * shot0];
    float* cnt  = stats + WS_CNT;
    float* ssum = stats + WS_SSUM;
    float* ssq  = stats + WS_SSQ;
    #pragma unroll
    for (int ct = 0; ct < 4; ++ct) {
        const int col = ncol0 + ct * 16 + ln;
        const float bv = b1[col];
        float s = 0.f, qq = 0.f;
        #pragma unroll
        for (int rt = 0; rt < 4; ++rt)
            #pragma unroll
            for (int rg = 0; rg < 4; ++rg) {
                const float h = acc[rt * 4 + ct][rg] + bv;
                s += h; qq += h * h;
            }
        s  += __shfl_xor(s, 16);  qq += __shfl_xor(qq, 16);
        s  += __shfl_xor(s, 32);  qq += __shfl_xor(qq, 32);
        if (lane < 16) {
            atomicAdd(&ssum[clsY * ED + col], s);
            atomicAdd(&ssq [clsY * ED + col], qq);
        }
    }
    if (tid == 0) atomicAdd(&cnt[clsY], 64.0f);
}

// =====================================================================
// Round-1 fp32 fallback (used only if ws_size is too small)
// =====================================================================
__device__ __forceinline__ int swz(int k, int r) { return k * 32 + (r ^ (k & 28)); }

__global__ __launch_bounds__(256) void kA(const float* __restrict__ x,
                                          const int* __restrict__ y,
                                          const float* __restrict__ W0,
                                          const float* __restrict__ b0,
                                          const float* __restrict__ W1,
                                          const float* __restrict__ b1,
                                          float* __restrict__ ws)
{
    __shared__ float lds[ED * 32];
    const int tid  = threadIdx.x;
    const int cls  = blockIdx.x & 127;
    const int seg  = blockIdx.x >> 7;
    const int base = seg * 32;
    {
        const int rr = tid >> 7;
        const int k4 = (tid & 127) * 4;
        for (int jj = 0; jj < 16; ++jj) {
            const int r = 2 * jj + rr;
            const long row = (long)cls + 128L * (base + r);
            const float4 xv = *(const float4*)(x + row * ED + k4);
            lds[swz(k4 + 0, r)] = xv.x;
            lds[swz(k4 + 1, r)] = xv.y;
            lds[swz(k4 + 2, r)] = xv.z;
            lds[swz(k4 + 3, r)] = xv.w;
        }
    }
    __syncthreads();
    const int c = tid;
    float acc0[32], acc1[32];
    #pragma unroll
    for (int r = 0; r < 32; ++r) { acc0[r] = 0.f; acc1[r] = 0.f; }
    #pragma unroll 2
    for (int k = 0; k < ED; ++k) {
        const float wa = W0[k * ED + c];
        const float wb = W0[k * ED + c + 256];
        #pragma unroll
        for (int rc = 0; rc < 32; rc += 4) {
            const float4 xv = *(const float4*)&lds[k * 32 + (rc ^ (k & 28))];
            acc0[rc+0] += xv.x * wa; acc1[rc+0] += xv.x * wb;
            acc0[rc+1] += xv.y * wa; acc1[rc+1] += xv.y * wb;
            acc0[rc+2] += xv.z * wa; acc1[rc+2] += xv.z * wb;
            acc0[rc+3] += xv.w * wa; acc1[rc+3] += xv.w * wb;
        }
    }
    const float ba = b0[c], bb = b0[c + 256];
    __syncthreads();
    #pragma unroll
    for (int rc = 0; rc < 32; rc += 4) {
        float4 v0, v1;
        v0.x = fmaxf(acc0[rc+0] + ba, 0.f); v0.y = fmaxf(acc0[rc+1] + ba, 0.f);
        v0.z = fmaxf(acc0[rc+2] + ba, 0.f); v0.w = fmaxf(acc0[rc+3] + ba, 0.f);
        v1.x = fmaxf(acc1[rc+0] + bb, 0.f); v1.y = fmaxf(acc1[rc+1] + bb, 0.f);
        v1.z = fmaxf(acc1[rc+2] + bb, 0.f); v1.w = fmaxf(acc1[rc+3] + bb, 0.f);
        *(float4*)&lds[c * 32 + (rc ^ (c & 28))] = v0;
        *(float4*)&lds[(c + 256) * 32 + (rc ^ (c & 28))] = v1;
    }
    __syncthreads();
    #pragma unroll
    for (int r = 0; r < 32; ++r) { acc0[r] = 0.f; acc1[r] = 0.f; }
    #pragma unroll 2
    for (int k = 0; k < ED; ++k) {
        const float wa = W1[k * ED + c];
        const float wb = W1[k * ED + c + 256];
        #pragma unroll
        for (int rc = 0; rc < 32; rc += 4) {
            const float4 tv = *(const float4*)&lds[k * 32 + (rc ^ (k & 28))];
            acc0[rc+0] += tv.x * wa; acc1[rc+0] += tv.x * wb;
            acc0[rc+1] += tv.y * wa; acc1[rc+1] += tv.y * wb;
            acc0[rc+2] += tv.z * wa; acc1[rc+2] += tv.z * wb;
            acc0[rc+3] += tv.w * wa; acc1[rc+3] += tv.w * wb;
        }
    }
    const float c0 = b1[c], c1 = b1[c + 256];
    #pragma unroll
    for (int r = 0; r < 32; ++r) { acc0[r] += c0; acc1[r] += c1; }
    const int y0 = y[(long)cls + 128L * base];
    bool uni = true;
    #pragma unroll
    for (int r = 1; r < 32; ++r) uni = uni && (y[(long)cls + 128L * (base + r)] == y0);
    float* cnt  = ws + WS_CNT;
    float* ssum = ws + WS_SSUM;
    float* ssq  = ws + WS_SSQ;
    if (uni) {
        float s0 = 0.f, q0 = 0.f, s1 = 0.f, q1 = 0.f;
        #pragma unroll
        for (int r = 0; r < 32; ++r) {
            s0 += acc0[r]; q0 += acc0[r] * acc0[r];
            s1 += acc1[r]; q1 += acc1[r] * acc1[r];
        }
        atomicAdd(&ssum[y0 * ED + c], s0);
        atomicAdd(&ssq [y0 * ED + c], q0);
        atomicAdd(&ssum[y0 * ED + c + 256], s1);
        atomicAdd(&ssq [y0 * ED + c + 256], q1);
        if (tid == 0) atomicAdd(&cnt[y0], 32.0f);
    } else {
        #pragma unroll
        for (int r = 0; r < 32; ++r) {
            const int yr = y[(long)cls + 128L * (base + r)];
            atomicAdd(&ssum[yr * ED + c], acc0[r]);
            atomicAdd(&ssq [yr * ED + c], acc0[r] * acc0[r]);
            atomicAdd(&ssum[yr * ED + c + 256], acc1[r]);
            atomicAdd(&ssq [yr * ED + c + 256], acc1[r] * acc1[r]);
        }
        if (tid == 0)
            for (int r = 0; r < 32; ++r)
                atomicAdd(&cnt[y[(long)cls + 128L * (base + r)]], 1.0f);
    }
}

// ---------------- Stage B1: per-class mean/var/mnorm + s/v MLP ----------------
__global__ __launch_bounds__(256) void kB1(const float* __restrict__ Ws,
                                           const float* __restrict__ bs,
                                           const float* __restrict__ Wv0,
                                           const float* __restrict__ bv0,
                                           const float* __restrict__ Wv1,
                                           const float* __restrict__ bv1,
                                           float* __restrict__ ws)
{
    __shared__ float sv[1025];
    __shared__ float red[256];
    __shared__ float sb[EMBD];
    __shared__ float pb[VDIM];
    const int cI = blockIdx.x, tid = threadIdx.x;
    const float* ssum = ws + WS_SSUM + cI * ED;
    const float* ssq  = ws + WS_SSQ  + cI * ED;
    const float cntv = ws[WS_CNT + cI];

    float nacc = 0.f;
    for (int e = tid; e < ED; e += 256) {
        const float m = ssum[e] / cntv;
        const float qv = ssq[e];
        const float var = (qv - cntv * m * m) / (cntv - 1.0f);
        sv[e] = var;
        sv[512 + e] = m;
        ws[WS_MEAN + cI * ED + e] = m;
        nacc += m * m;
    }
    if (tid == 0) {
        const float Ncv = (cntv - 1.0f) / 1023.0f;
        sv[1024] = Ncv;
        ws[WS_NC + cI] = Ncv;
    }
    red[tid] = nacc;
    __syncthreads();
    for (int off = 128; off > 0; off >>= 1) {
        if (tid < off) red[tid] += red[tid + off];
        __syncthreads();
    }
    const float inv = 1.0f / fmaxf(sqrtf(red[0]), 1e-7f);
    for (int e = tid; e < ED; e += 256)
        ws[WS_MNORM + cI * ED + e] = sv[512 + e] * inv;
    __syncthreads();

    if (tid < EMBD) {
        float a = bs[tid];
        for (int k = 0; k < 1025; ++k) a += sv[k] * Ws[k * EMBD + tid];
        sb[tid] = fmaxf(a, 0.f);
    }
    __syncthreads();
    if (tid < VDIM) {
        float a = bv0[tid];
        for (int k = 0; k < EMBD; ++k) a += sb[k] * Wv0[k * VDIM + tid];
        pb[tid] = fmaxf(a, 0.f);
    }
    __syncthreads();
    if (tid < VDIM) {
        float a = bv1[tid];
        for (int k = 0; k < VDIM; ++k) a += pb[k] * Wv1[k * VDIM + tid];
        ws[WS_V + cI * VDIM + tid] = a;
    }
}

// ---------------- Stage B2: weighted pairwise-cos partial sums ----------------
__global__ __launch_bounds__(128) void kB2(float* __restrict__ ws)
{
    __shared__ float mi[ED];
    __shared__ float red[128];
    const int i = blockIdx.x, tid = threadIdx.x;
    const float* mn = ws + WS_MNORM;
    for (int e = tid; e < ED; e += 128) mi[e] = mn[i * ED + e];
    __syncthreads();
    float contrib = 0.f;
    if (tid > i) {
        float d = 0.f;
        for (int e = 0; e < ED; ++e) d += mi[e] * mn[tid * ED + e];
        contrib = (float)(tid - i) * d;
    }
    red[tid] = contrib;
    __syncthreads();
    for (int off = 64; off > 0; off >>= 1) {
        if (tid < off) red[tid] += red[tid + off];
        __syncthreads();
    }
    if (tid == 0) ws[WS_SIMP + i] = red[0];
}

// ---------------- Stage B3: vv -> task -> cluster read-out ----------------
__global__ __launch_bounds__(128) void kB3(const float* __restrict__ W2,
                                           const float* __restrict__ b2,
                                           const float* __restrict__ mem,
                                           float* __restrict__ ws,
                                           float* __restrict__ out)
{
    __shared__ float vv[2 * VDIM + 2];
    __shared__ float task[TASKD];
    __shared__ float Cr[KCLUST];
    __shared__ float rsum;
    const int tid = threadIdx.x;
    const float* v = ws + WS_V;

    if (tid < VDIM) {
        float me = 0.f;
        for (int c = 0; c < NCLASS; ++c) me += v[c * VDIM + tid];
        me /= (float)NCLASS;
        float va = 0.f;
        for (int c = 0; c < NCLASS; ++c) {
            const float d = v[c * VDIM + tid] - me;
            va += d * d;
        }
        va /= (float)(NCLASS - 1);
        vv[tid] = va;
        vv[VDIM + tid] = me;
    }
    if (tid == 32 + VDIM) {
        float a = 0.f;
        for (int c = 0; c < NCLASS; ++c) a += ws[WS_NC + c];
        vv[2 * VDIM] = a / (float)NCLASS;
    }
    if (tid == 33 + VDIM) {
        float a = 0.f;
        for (int i = 0; i < NCLASS; ++i) a += ws[WS_SIMP + i];
        vv[2 * VDIM + 1] = a;
    }
    __syncthreads();
    if (tid < TASKD) {
        float a = b2[tid];
        for (int k = 0; k < 2 * VDIM + 2; ++k) a += vv[k] * W2[k * TASKD + tid];
        task[tid] = fmaxf(a, 0.f);
    }
    __syncthreads();
    if (tid < KCLUST) {
        float dd = 0.f;
        for (int e = 0; e < TASKD; ++e) {
            const float df = task[e] - mem[tid * TASKD + e];
            dd += df * df;
        }
        const float d = sqrtf(dd);
        Cr[tid] = 1.0f / (d + 1.0f);    // TEMP=1: (d+1)^-1
    }
    __syncthreads();
    if (tid == 0) {
        float a = 0.f;
        for (int k = 0; k < KCLUST; ++k) a += Cr[k];
        rsum = a;
    }
    __syncthreads();
    if (tid < TASKD) {
        float a = 0.f;
        for (int k = 0; k < KCLUST; ++k) a += (Cr[k] / rsum) * mem[k * TASKD + tid];
        out[tid] = a;
    }
}

extern "C" void kernel_launch(void* const* d_in, const int* in_sizes, int n_in,
                              void* d_out, int out_size, void* d_ws, size_t ws_size,
                              hipStream_t stream)
{
    const float* x   = (const float*)d_in[0];
    const int*   y   = (const int*)  d_in[1];
    const float* W0  = (const float*)d_in[2];
    const float* b0  = (const float*)d_in[3];
    const float* W1  = (const float*)d_in[4];
    const float* b1  = (const float*)d_in[5];
    const float* Ws  = (const float*)d_in[6];
    const float* bs  = (const float*)d_in[7];
    const float* Wv0 = (const float*)d_in[8];
    const float* bv0 = (const float*)d_in[9];
    const float* Wv1 = (const float*)d_in[10];
    const float* bv1 = (const float*)d_in[11];
    const float* W2  = (const float*)d_in[12];
    const float* b2  = (const float*)d_in[13];
    const float* mem = (const float*)d_in[14];
    float* out = (float*)d_out;

    if (ws_size >= WS_NEEDED) {
        char* wsb = (char*)d_ws;
        f16* w0h = (f16*)(wsb + OFF_W0H);
        f16* w0l = (f16*)(wsb + OFF_W0L);
        f16* w1h = (f16*)(wsb + OFF_W1H);
        f16* w1l = (f16*)(wsb + OFF_W1L);
        float* stats = (float*)(wsb + OFF_STATS);

        hipMemsetAsync(stats, 0, (size_t)WS_SIMP * sizeof(float), stream);
        hipLaunchKernelGGL(kPrep, dim3(2 * ED * ED / 256), dim3(256), 0, stream,
                           W0, W1, w0h, w0l, w1h, w1l);
        hipLaunchKernelGGL(kFused, dim3(NROWS / 64), dim3(512), 0, stream,
                           x, y, w0h, w0l, b0, w1h, w1l, b1, stats);
        hipLaunchKernelGGL(kB1, dim3(NCLASS), dim3(256), 0, stream, Ws, bs, Wv0, bv0, Wv1, bv1, stats);
        hipLaunchKernelGGL(kB2, dim3(NCLASS), dim3(128), 0, stream, stats);
        hipLaunchKernelGGL(kB3, dim3(1), dim3(128), 0, stream, W2, b2, mem, stats, out);
    } else {
        float* ws = (float*)d_ws;
        hipMemsetAsync(ws, 0, (size_t)WS_SIMP * sizeof(float), stream);
        hipLaunchKernelGGL(kA,  dim3(NROWS / 32), dim3(256), 0, stream, x, y, W0, b0, W1, b1, ws);
        hipLaunchKernelGGL(kB1, dim3(NCLASS), dim3(256), 0, stream, Ws, bs, Wv0, bv0, Wv1, bv1, ws);
        hipLaunchKernelGGL(kB2, dim3(NCLASS), dim3(128), 0, stream, ws);
        hipLaunchKernelGGL(kB3, dim3(1), dim3(128), 0, stream, W2, b2, mem, ws, out);
    }
}

// Round 4
// 793.705 us; speedup vs baseline: 2.6950x; 1.1694x over previous
//
#include <hip/hip_runtime.h>
#include <math.h>

typedef _Float16 f16;
typedef _Float16 f16x8 __attribute__((ext_vector_type(8)));
typedef _Float16 f16x4 __attribute__((ext_vector_type(4)));
typedef float f32x4 __attribute__((ext_vector_type(4)));

// Problem constants
#define NCLASS   128
#define ED       512        // E = FEAT*EMB
#define NROWS    131072     // N
#define EMBD     64
#define VDIM     32
#define TASKD    64
#define KCLUST   32

// ---- workspace byte layout (fast path): W splits + stats only ----
#define OFF_W0H  0ull
#define OFF_W0L  (OFF_W0H + (size_t)ED*ED*2)
#define OFF_W1H  (OFF_W0L + (size_t)ED*ED*2)
#define OFF_W1L  (OFF_W1H + (size_t)ED*ED*2)
#define OFF_STATS (OFF_W1L + (size_t)ED*ED*2)

// float offsets inside the stats region
#define WS_CNT   0
#define WS_SSUM  128
#define WS_SSQ   (128 + 65536)
#define WS_SIMP  (128 + 2*65536)
#define WS_MEAN  (WS_SIMP + 128)
#define WS_MNORM (WS_MEAN + 65536)
#define WS_NC    (WS_MNORM + 65536)
#define WS_V     (WS_NC + 128)
#define STATS_FLOATS (WS_V + NCLASS*VDIM)
#define WS_NEEDED (OFF_STATS + (size_t)STATS_FLOATS*4)

// =====================================================================
// Prep: split W0/W1 into f16 hi/lo, k-packed layout Wp[((k>>3)*512+n)*8+(k&7)]
// so a B-fragment (8 consecutive k at fixed n) is one contiguous 16-B load.
// =====================================================================
__global__ __launch_bounds__(256) void kPrep(const float* __restrict__ W0,
                                             const float* __restrict__ W1,
                                             f16* __restrict__ w0h, f16* __restrict__ w0l,
                                             f16* __restrict__ w1h, f16* __restrict__ w1l)
{
    const int idx = blockIdx.x * 256 + threadIdx.x;    // 0 .. 2*512*512-1
    const int sel = idx >= ED * ED;
    const float* W = sel ? W1 : W0;
    f16* oh = sel ? w1h : w0h;
    f16* ol = sel ? w1l : w0l;
    const int e = idx & (ED * ED - 1);
    const int k = e >> 9, n = e & 511;
    const float w = W[e];
    const f16 hi = (f16)w;
    const f16 lo = (f16)(w - (float)hi);
    const int o = ((k >> 3) * ED + n) * 8 + (k & 7);
    oh[o] = hi;
    ol[o] = lo;
}

// =====================================================================
// Fused kernel, round 4: register-double-buffered k-loop + XOR-swizzled LDS.
// LDS layout: Th/Tl[row][kb^(row&7)][k&7], row stride 512 halfs (1024 B).
// Fragment reads: 16 lanes -> banks 4*((kb^(ln&7))%8), each bank-quad 2-way
// (free per m136). 128 KiB LDS total -> still 1 block/CU.
// =====================================================================
__global__ __launch_bounds__(512, 2) void kFused(
    const float* __restrict__ x,
    const int*   __restrict__ y,
    const f16*  __restrict__ w0h, const f16* __restrict__ w0l,
    const float* __restrict__ b0,
    const f16*  __restrict__ w1h, const f16* __restrict__ w1l,
    const float* __restrict__ b1,
    float* __restrict__ stats)
{
    __shared__ f16 Th[64 * 512];   // 65,536 B
    __shared__ f16 Tl[64 * 512];   // 65,536 B

    const int tid  = threadIdx.x;
    const int lane = tid & 63;
    const int wid  = tid >> 6;          // 0..7 = column group
    const int q    = lane >> 4;         // quad 0..3 -> k-sub-block
    const int ln   = lane & 15;
    const int ncol0 = wid * 64;

    const int cls   = blockIdx.x >> 4;          // v0>>10, v0 = blockIdx.x*64
    const int shot0 = (blockIdx.x & 15) * 64;   // v0 & 1023

// ---- fragment load/compute macros (keep LDS address-space addressing) ----
#define LOADA(aH_, aL_, ks_) do {                                         \
    const int pkb_ = (((ks_) * 4 + q) ^ (ln & 7)) * 8;                    \
    _Pragma("unroll")                                                     \
    for (int rt_ = 0; rt_ < 4; ++rt_) {                                   \
        const int ba_ = (rt_ * 16 + ln) * 512 + pkb_;                     \
        aH_[rt_] = *(const f16x8*)&Th[ba_];                               \
        aL_[rt_] = *(const f16x8*)&Tl[ba_];                               \
    } } while (0)

#define LOADB(bH_, bL_, wh_, wl_, ks_) do {                               \
    const int kb_ = ((ks_) * 4 + q) * ED + ncol0 + ln;                    \
    _Pragma("unroll")                                                     \
    for (int ct_ = 0; ct_ < 4; ++ct_) {                                   \
        const int bo_ = (kb_ + ct_ * 16) * 8;                             \
        bH_[ct_] = *(const f16x8*)(wh_ + bo_);                            \
        bL_[ct_] = *(const f16x8*)(wl_ + bo_);                            \
    } } while (0)

#define DOMFMA(aH_, aL_, bH_, bL_) do {                                   \
    _Pragma("unroll")                                                     \
    for (int ct_ = 0; ct_ < 4; ++ct_) {                                   \
        _Pragma("unroll")                                                 \
        for (int rt_ = 0; rt_ < 4; ++rt_) {                               \
            f32x4 c_ = acc[rt_ * 4 + ct_];                                \
            c_ = __builtin_amdgcn_mfma_f32_16x16x32_f16(aL_[rt_], bH_[ct_], c_, 0, 0, 0); \
            c_ = __builtin_amdgcn_mfma_f32_16x16x32_f16(aH_[rt_], bL_[ct_], c_, 0, 0, 0); \
            c_ = __builtin_amdgcn_mfma_f32_16x16x32_f16(aH_[rt_], bH_[ct_], c_, 0, 0, 0); \
            acc[rt_ * 4 + ct_] = c_;                                      \
        } } } while (0)

    // ---- phase 0: stage x-tile (64x512), split into f16 hi/lo ----
    #pragma unroll
    for (int i = 0; i < 16; ++i) {
        const int flat = tid + i * 512;         // 0..8191 float4s
        const int row  = flat >> 7;             // 128 float4 per row
        const int f    = flat & 127;
        const long orig = (long)cls + 128L * (shot0 + row);
        const float4 xv = *(const float4*)(x + orig * ED + f * 4);
        f16x4 hv, lv;
        hv[0] = (f16)xv.x; lv[0] = (f16)(xv.x - (float)hv[0]);
        hv[1] = (f16)xv.y; lv[1] = (f16)(xv.y - (float)hv[1]);
        hv[2] = (f16)xv.z; lv[2] = (f16)(xv.z - (float)hv[2]);
        hv[3] = (f16)xv.w; lv[3] = (f16)(xv.w - (float)hv[3]);
        const int ha = row * 512 + (((f >> 1) ^ (row & 7)) << 3) + ((f & 1) << 2);
        *(f16x4*)&Th[ha] = hv;
        *(f16x4*)&Tl[ha] = lv;
    }

    f32x4 acc[16];
    #pragma unroll
    for (int i = 0; i < 16; ++i) acc[i] = (f32x4){0.f, 0.f, 0.f, 0.f};

    f16x8 aH0[4], aL0[4], bH0[4], bL0[4];
    f16x8 aH1[4], aL1[4], bH1[4], bL1[4];

    // prefetch B(0) before the barrier (no LDS dependency)
    LOADB(bH0, bL0, w0h, w0l, 0);
    __syncthreads();
    LOADA(aH0, aL0, 0);

    // ---- phase 1: GEMM1, double-buffered ----
    #pragma unroll 1
    for (int ks = 0; ks < 14; ks += 2) {
        LOADB(bH1, bL1, w0h, w0l, ks + 1);
        LOADA(aH1, aL1, ks + 1);
        DOMFMA(aH0, aL0, bH0, bL0);
        LOADB(bH0, bL0, w0h, w0l, ks + 2);
        LOADA(aH0, aL0, ks + 2);
        DOMFMA(aH1, aL1, bH1, bL1);
    }
    LOADB(bH1, bL1, w0h, w0l, 15);
    LOADA(aH1, aL1, 15);
    DOMFMA(aH0, aL0, bH0, bL0);
    DOMFMA(aH1, aL1, bH1, bL1);

    __syncthreads();   // everyone done reading x-tile

    // ---- write t = relu(acc+b0) split back into the same LDS tile ----
    // C/D layout (16x16): m = q*4 + reg, n = lane&15
    #pragma unroll
    for (int ct = 0; ct < 4; ++ct) {
        const int col = ncol0 + ct * 16 + ln;
        const float bv = b0[col];
        const int kbx = col >> 3, ko = col & 7;
        #pragma unroll
        for (int rt = 0; rt < 4; ++rt) {
            #pragma unroll
            for (int rg = 0; rg < 4; ++rg) {
                const int row = rt * 16 + q * 4 + rg;
                const float t = fmaxf(acc[rt * 4 + ct][rg] + bv, 0.f);
                const f16 hi = (f16)t;
                const f16 lo = (f16)(t - (float)hi);
                const int a = row * 512 + ((kbx ^ (row & 7)) << 3) + ko;
                Th[a] = hi;
                Tl[a] = lo;
            }
        }
    }

    #pragma unroll
    for (int i = 0; i < 16; ++i) acc[i] = (f32x4){0.f, 0.f, 0.f, 0.f};

    // prefetch GEMM2 B(0) across the barrier
    LOADB(bH0, bL0, w1h, w1l, 0);
    __syncthreads();   // t-tile complete
    LOADA(aH0, aL0, 0);

    // ---- phase 2: GEMM2, double-buffered ----
    #pragma unroll 1
    for (int ks = 0; ks < 14; ks += 2) {
        LOADB(bH1, bL1, w1h, w1l, ks + 1);
        LOADA(aH1, aL1, ks + 1);
        DOMFMA(aH0, aL0, bH0, bL0);
        LOADB(bH0, bL0, w1h, w1l, ks + 2);
        LOADA(aH0, aL0, ks + 2);
        DOMFMA(aH1, aL1, bH1, bL1);
    }
    LOADB(bH1, bL1, w1h, w1l, 15);
    LOADA(aH1, aL1, 15);
    DOMFMA(aH0, aL0, bH0, bL0);
    DOMFMA(aH1, aL1, bH1, bL1);

    // ---- epilogue: per-class stats (all 64 rows are one class) ----
    const int clsY = y[(long)cls + 128L * shot0];
    float* cnt  = stats + WS_CNT;
    float* ssum = stats + WS_SSUM;
    float* ssq  = stats + WS_SSQ;
    #pragma unroll
    for (int ct = 0; ct < 4; ++ct) {
        const int col = ncol0 + ct * 16 + ln;
        const float bv = b1[col];
        float s = 0.f, qq = 0.f;
        #pragma unroll
        for (int rt = 0; rt < 4; ++rt)
            #pragma unroll
            for (int rg = 0; rg < 4; ++rg) {
                const float h = acc[rt * 4 + ct][rg] + bv;
                s += h; qq += h * h;
            }
        s  += __shfl_xor(s, 16);  qq += __shfl_xor(qq, 16);
        s  += __shfl_xor(s, 32);  qq += __shfl_xor(qq, 32);
        if (lane < 16) {
            atomicAdd(&ssum[clsY * ED + col], s);
            atomicAdd(&ssq [clsY * ED + col], qq);
        }
    }
    if (tid == 0) atomicAdd(&cnt[clsY], 64.0f);

#undef LOADA
#undef LOADB
#undef DOMFMA
}

// =====================================================================
// Round-1 fp32 fallback (used only if ws_size is too small)
// =====================================================================
__device__ __forceinline__ int swz(int k, int r) { return k * 32 + (r ^ (k & 28)); }

__global__ __launch_bounds__(256) void kA(const float* __restrict__ x,
                                          const int* __restrict__ y,
                                          const float* __restrict__ W0,
                                          const float* __restrict__ b0,
                                          const float* __restrict__ W1,
                                          const float* __restrict__ b1,
                                          float* __restrict__ ws)
{
    __shared__ float lds[ED * 32];
    const int tid  = threadIdx.x;
    const int cls  = blockIdx.x & 127;
    const int seg  = blockIdx.x >> 7;
    const int base = seg * 32;
    {
        const int rr = tid >> 7;
        const int k4 = (tid & 127) * 4;
        for (int jj = 0; jj < 16; ++jj) {
            const int r = 2 * jj + rr;
            const long row = (long)cls + 128L * (base + r);
            const float4 xv = *(const float4*)(x + row * ED + k4);
            lds[swz(k4 + 0, r)] = xv.x;
            lds[swz(k4 + 1, r)] = xv.y;
            lds[swz(k4 + 2, r)] = xv.z;
            lds[swz(k4 + 3, r)] = xv.w;
        }
    }
    __syncthreads();
    const int c = tid;
    float acc0[32], acc1[32];
    #pragma unroll
    for (int r = 0; r < 32; ++r) { acc0[r] = 0.f; acc1[r] = 0.f; }
    #pragma unroll 2
    for (int k = 0; k < ED; ++k) {
        const float wa = W0[k * ED + c];
        const float wb = W0[k * ED + c + 256];
        #pragma unroll
        for (int rc = 0; rc < 32; rc += 4) {
            const float4 xv = *(const float4*)&lds[k * 32 + (rc ^ (k & 28))];
            acc0[rc+0] += xv.x * wa; acc1[rc+0] += xv.x * wb;
            acc0[rc+1] += xv.y * wa; acc1[rc+1] += xv.y * wb;
            acc0[rc+2] += xv.z * wa; acc1[rc+2] += xv.z * wb;
            acc0[rc+3] += xv.w * wa; acc1[rc+3] += xv.w * wb;
        }
    }
    const float ba = b0[c], bb = b0[c + 256];
    __syncthreads();
    #pragma unroll
    for (int rc = 0; rc < 32; rc += 4) {
        float4 v0, v1;
        v0.x = fmaxf(acc0[rc+0] + ba, 0.f); v0.y = fmaxf(acc0[rc+1] + ba, 0.f);
        v0.z = fmaxf(acc0[rc+2] + ba, 0.f); v0.w = fmaxf(acc0[rc+3] + ba, 0.f);
        v1.x = fmaxf(acc1[rc+0] + bb, 0.f); v1.y = fmaxf(acc1[rc+1] + bb, 0.f);
        v1.z = fmaxf(acc1[rc+2] + bb, 0.f); v1.w = fmaxf(acc1[rc+3] + bb, 0.f);
        *(float4*)&lds[c * 32 + (rc ^ (c & 28))] = v0;
        *(float4*)&lds[(c + 256) * 32 + (rc ^ (c & 28))] = v1;
    }
    __syncthreads();
    #pragma unroll
    for (int r = 0; r < 32; ++r) { acc0[r] = 0.f; acc1[r] = 0.f; }
    #pragma unroll 2
    for (int k = 0; k < ED; ++k) {
        const float wa = W1[k * ED + c];
        const float wb = W1[k * ED + c + 256];
        #pragma unroll
        for (int rc = 0; rc < 32; rc += 4) {
            const float4 tv = *(const float4*)&lds[k * 32 + (rc ^ (k & 28))];
            acc0[rc+0] += tv.x * wa; acc1[rc+0] += tv.x * wb;
            acc0[rc+1] += tv.y * wa; acc1[rc+1] += tv.y * wb;
            acc0[rc+2] += tv.z * wa; acc1[rc+2] += tv.z * wb;
            acc0[rc+3] += tv.w * wa; acc1[rc+3] += tv.w * wb;
        }
    }
    const float c0 = b1[c], c1 = b1[c + 256];
    #pragma unroll
    for (int r = 0; r < 32; ++r) { acc0[r] += c0; acc1[r] += c1; }
    const int y0 = y[(long)cls + 128L * base];
    bool uni = true;
    #pragma unroll
    for (int r = 1; r < 32; ++r) uni = uni && (y[(long)cls + 128L * (base + r)] == y0);
    float* cnt  = ws + WS_CNT;
    float* ssum = ws + WS_SSUM;
    float* ssq  = ws + WS_SSQ;
    if (uni) {
        float s0 = 0.f, q0 = 0.f, s1 = 0.f, q1 = 0.f;
        #pragma unroll
        for (int r = 0; r < 32; ++r) {
            s0 += acc0[r]; q0 += acc0[r] * acc0[r];
            s1 += acc1[r]; q1 += acc1[r] * acc1[r];
        }
        atomicAdd(&ssum[y0 * ED + c], s0);
        atomicAdd(&ssq [y0 * ED + c], q0);
        atomicAdd(&ssum[y0 * ED + c + 256], s1);
        atomicAdd(&ssq [y0 * ED + c + 256], q1);
        if (tid == 0) atomicAdd(&cnt[y0], 32.0f);
    } else {
        #pragma unroll
        for (int r = 0; r < 32; ++r) {
            const int yr = y[(long)cls + 128L * (base + r)];
            atomicAdd(&ssum[yr * ED + c], acc0[r]);
            atomicAdd(&ssq [yr * ED + c], acc0[r] * acc0[r]);
            atomicAdd(&ssum[yr * ED + c + 256], acc1[r]);
            atomicAdd(&ssq [yr * ED + c + 256], acc1[r] * acc1[r]);
        }
        if (tid == 0)
            for (int r = 0; r < 32; ++r)
                atomicAdd(&cnt[y[(long)cls + 128L * (base + r)]], 1.0f);
    }
}

// ---------------- Stage B1: per-class mean/var/mnorm + s/v MLP ----------------
__global__ __launch_bounds__(256) void kB1(const float* __restrict__ Ws,
                                           const float* __restrict__ bs,
                                           const float* __restrict__ Wv0,
                                           const float* __restrict__ bv0,
                                           const float* __restrict__ Wv1,
                                           const float* __restrict__ bv1,
                                           float* __restrict__ ws)
{
    __shared__ float sv[1025];
    __shared__ float red[256];
    __shared__ float sb[EMBD];
    __shared__ float pb[VDIM];
    const int cI = blockIdx.x, tid = threadIdx.x;
    const float* ssum = ws + WS_SSUM + cI * ED;
    const float* ssq  = ws + WS_SSQ  + cI * ED;
    const float cntv = ws[WS_CNT + cI];

    float nacc = 0.f;
    for (int e = tid; e < ED; e += 256) {
        const float m = ssum[e] / cntv;
        const float qv = ssq[e];
        const float var = (qv - cntv * m * m) / (cntv - 1.0f);
        sv[e] = var;
        sv[512 + e] = m;
        ws[WS_MEAN + cI * ED + e] = m;
        nacc += m * m;
    }
    if (tid == 0) {
        const float Ncv = (cntv - 1.0f) / 1023.0f;
        sv[1024] = Ncv;
        ws[WS_NC + cI] = Ncv;
    }
    red[tid] = nacc;
    __syncthreads();
    for (int off = 128; off > 0; off >>= 1) {
        if (tid < off) red[tid] += red[tid + off];
        __syncthreads();
    }
    const float inv = 1.0f / fmaxf(sqrtf(red[0]), 1e-7f);
    for (int e = tid; e < ED; e += 256)
        ws[WS_MNORM + cI * ED + e] = sv[512 + e] * inv;
    __syncthreads();

    if (tid < EMBD) {
        float a = bs[tid];
        for (int k = 0; k < 1025; ++k) a += sv[k] * Ws[k * EMBD + tid];
        sb[tid] = fmaxf(a, 0.f);
    }
    __syncthreads();
    if (tid < VDIM) {
        float a = bv0[tid];
        for (int k = 0; k < EMBD; ++k) a += sb[k] * Wv0[k * VDIM + tid];
        pb[tid] = fmaxf(a, 0.f);
    }
    __syncthreads();
    if (tid < VDIM) {
        float a = bv1[tid];
        for (int k = 0; k < VDIM; ++k) a += pb[k] * Wv1[k * VDIM + tid];
        ws[WS_V + cI * VDIM + tid] = a;
    }
}

// ---------------- Stage B2: weighted pairwise-cos partial sums ----------------
__global__ __launch_bounds__(128) void kB2(float* __restrict__ ws)
{
    __shared__ float mi[ED];
    __shared__ float red[128];
    const int i = blockIdx.x, tid = threadIdx.x;
    const float* mn = ws + WS_MNORM;
    for (int e = tid; e < ED; e += 128) mi[e] = mn[i * ED + e];
    __syncthreads();
    float contrib = 0.f;
    if (tid > i) {
        const float* rowj = mn + tid * ED;
        float d = 0.f;
        for (int e = 0; e < ED; e += 4) {
            const float4 a = *(const float4*)&mi[e];
            const float4 b = *(const float4*)&rowj[e];
            d += a.x * b.x + a.y * b.y + a.z * b.z + a.w * b.w;
        }
        contrib = (float)(tid - i) * d;
    }
    red[tid] = contrib;
    __syncthreads();
    for (int off = 64; off > 0; off >>= 1) {
        if (tid < off) red[tid] += red[tid + off];
        __syncthreads();
    }
    if (tid == 0) ws[WS_SIMP + i] = red[0];
}

// ---------------- Stage B3: vv -> task -> cluster read-out ----------------
__global__ __launch_bounds__(128) void kB3(const float* __restrict__ W2,
                                           const float* __restrict__ b2,
                                           const float* __restrict__ mem,
                                           float* __restrict__ ws,
                                           float* __restrict__ out)
{
    __shared__ float vv[2 * VDIM + 2];
    __shared__ float task[TASKD];
    __shared__ float Cr[KCLUST];
    __shared__ float rsum;
    const int tid = threadIdx.x;
    const float* v = ws + WS_V;

    if (tid < VDIM) {
        float me = 0.f;
        for (int c = 0; c < NCLASS; ++c) me += v[c * VDIM + tid];
        me /= (float)NCLASS;
        float va = 0.f;
        for (int c = 0; c < NCLASS; ++c) {
            const float d = v[c * VDIM + tid] - me;
            va += d * d;
        }
        va /= (float)(NCLASS - 1);
        vv[tid] = va;
        vv[VDIM + tid] = me;
    }
    if (tid == 32 + VDIM) {
        float a = 0.f;
        for (int c = 0; c < NCLASS; ++c) a += ws[WS_NC + c];
        vv[2 * VDIM] = a / (float)NCLASS;
    }
    if (tid == 33 + VDIM) {
        float a = 0.f;
        for (int i = 0; i < NCLASS; ++i) a += ws[WS_SIMP + i];
        vv[2 * VDIM + 1] = a;
    }
    __syncthreads();
    if (tid < TASKD) {
        float a = b2[tid];
        for (int k = 0; k < 2 * VDIM + 2; ++k) a += vv[k] * W2[k * TASKD + tid];
        task[tid] = fmaxf(a, 0.f);
    }
    __syncthreads();
    if (tid < KCLUST) {
        float dd = 0.f;
        for (int e = 0; e < TASKD; ++e) {
            const float df = task[e] - mem[tid * TASKD + e];
            dd += df * df;
        }
        const float d = sqrtf(dd);
        Cr[tid] = 1.0f / (d + 1.0f);    // TEMP=1: (d+1)^-1
    }
    __syncthreads();
    if (tid == 0) {
        float a = 0.f;
        for (int k = 0; k < KCLUST; ++k) a += Cr[k];
        rsum = a;
    }
    __syncthreads();
    if (tid < TASKD) {
        float a = 0.f;
        for (int k = 0; k < KCLUST; ++k) a += (Cr[k] / rsum) * mem[k * TASKD + tid];
        out[tid] = a;
    }
}

extern "C" void kernel_launch(void* const* d_in, const int* in_sizes, int n_in,
                              void* d_out, int out_size, void* d_ws, size_t ws_size,
                              hipStream_t stream)
{
    const float* x   = (const float*)d_in[0];
    const int*   y   = (const int*)  d_in[1];
    const float* W0  = (const float*)d_in[2];
    const float* b0  = (const float*)d_in[3];
    const float* W1  = (const float*)d_in[4];
    const float* b1  = (const float*)d_in[5];
    const float* Ws  = (const float*)d_in[6];
    const float* bs  = (const float*)d_in[7];
    const float* Wv0 = (const float*)d_in[8];
    const float* bv0 = (const float*)d_in[9];
    const float* Wv1 = (const float*)d_in[10];
    const float* bv1 = (const float*)d_in[11];
    const float* W2  = (const float*)d_in[12];
    const float* b2  = (const float*)d_in[13];
    const float* mem = (const float*)d_in[14];
    float* out = (float*)d_out;

    if (ws_size >= WS_NEEDED) {
        char* wsb = (char*)d_ws;
        f16* w0h = (f16*)(wsb + OFF_W0H);
        f16* w0l = (f16*)(wsb + OFF_W0L);
        f16* w1h = (f16*)(wsb + OFF_W1H);
        f16* w1l = (f16*)(wsb + OFF_W1L);
        float* stats = (float*)(wsb + OFF_STATS);

        hipMemsetAsync(stats, 0, (size_t)WS_SIMP * sizeof(float), stream);
        hipLaunchKernelGGL(kPrep, dim3(2 * ED * ED / 256), dim3(256), 0, stream,
                           W0, W1, w0h, w0l, w1h, w1l);
        hipLaunchKernelGGL(kFused, dim3(NROWS / 64), dim3(512), 0, stream,
                           x, y, w0h, w0l, b0, w1h, w1l, b1, stats);
        hipLaunchKernelGGL(kB1, dim3(NCLASS), dim3(256), 0, stream, Ws, bs, Wv0, bv0, Wv1, bv1, stats);
        hipLaunchKernelGGL(kB2, dim3(NCLASS), dim3(128), 0, stream, stats);
        hipLaunchKernelGGL(kB3, dim3(1), dim3(128), 0, stream, W2, b2, mem, stats, out);
    } else {
        float* ws = (float*)d_ws;
        hipMemsetAsync(ws, 0, (size_t)WS_SIMP * sizeof(float), stream);
        hipLaunchKernelGGL(kA,  dim3(NROWS / 32), dim3(256), 0, stream, x, y, W0, b0, W1, b1, ws);
        hipLaunchKernelGGL(kB1, dim3(NCLASS), dim3(256), 0, stream, Ws, bs, Wv0, bv0, Wv1, bv1, ws);
        hipLaunchKernelGGL(kB2, dim3(NCLASS), dim3(128), 0, stream, ws);
        hipLaunchKernelGGL(kB3, dim3(1), dim3(128), 0, stream, W2, b2, mem, ws, out);
    }
}